// Round 3
// baseline (101.463 us; speedup 1.0000x reference)
//
#include <hip/hip_runtime.h>
#include <hip/hip_fp16.h>
#include <stdint.h>

#define N 512
#define NA 180
#define PP 708          // padded image pitch (dwords = vertical-pair texels)
#define PR 704          // padded image rows
#define POFF 96         // padded index of image row/col 0

// d_ws float-offsets (layout unchanged from verified baseline)
#define WS_IMGVP  0
#define WS_IMGVPT (PR * PP)                 // 498432
#define WS_TAB    (2 * PR * PP)             // 996864 (16B aligned)
#define WS_FLAGS  (WS_TAB + 4 * NA)

typedef _Float16 hh2 __attribute__((ext_vector_type(2)));
union H2U { uint32_t u; hh2 h; };

__device__ __forceinline__ hh2 cvt_pkrtz(float a, float b) {
    return __builtin_bit_cast(hh2, __builtin_amdgcn_cvt_pkrtz(a, b));
}

// Tiled pad: 22x22 blocks of 32x32. Builds VERTICAL-pair fp16 images:
//   imgVP [r][c] = (h(P[r][c]),  h(P[r+1][c]))      (P = zero-padded img)
//   imgVPT[r][c] = (h(PT[r][c]), h(PT[r+1][c]))     (PT = zero-padded img^T)
// so one bilinear sample = two adjacent dwords at (iv, iu), (iv, iu+1):
// each dword is a (top,bottom) f16 pair -> one v_dot2_f32_f16 per column.
// Also writes the per-angle affine table. All global accesses coalesced.
__global__ __launch_bounds__(256) void pad_kernel(const float* __restrict__ img,
                                                  const int* __restrict__ angles,
                                                  uint32_t* __restrict__ imgVP,
                                                  uint32_t* __restrict__ imgVPT,
                                                  float4* __restrict__ tab,
                                                  int* __restrict__ flags) {
    __shared__ float lds[33 * 34];   // pitch 34
    const int tid = threadIdx.x;
    const int bx = blockIdx.x, by = blockIdx.y;

    if (bx == 0 && by == 0 && tid < NA) {
        float t = (float)angles[tid] * 0.017453292519943295f;
        float si = sinf(t), co = cosf(t);
        int useT = fabsf(si) > fabsf(co);
        float4 e;
        if (useT) { e.x = co; e.y = -si; e.z = si; e.w = co; }
        else      { e.x = si; e.y = co;  e.z = co; e.w = -si; }
        tab[tid] = e;                // (au, bus, av, bvs)
        flags[tid] = useT;
    }

    // stage 33x33 of the padded image: padded coords (by*32+r, bx*32+c)
    for (int idx = tid; idx < 33 * 33; idx += 256) {
        int r = idx / 33, cc = idx - r * 33;
        int y = by * 32 + r - POFF, x = bx * 32 + cc - POFF;
        bool in = ((unsigned)y < N) && ((unsigned)x < N);
        lds[r * 34 + cc] = in ? img[y * N + x] : 0.0f;
    }
    __syncthreads();
    const int r0 = tid >> 5, cl = tid & 31;
#pragma unroll
    for (int j = 0; j < 4; ++j) {
        int row = j * 8 + r0;
        // vertical pair of P at (by*32+row, bx*32+cl)
        float v0 = lds[row * 34 + cl], v1 = lds[(row + 1) * 34 + cl];
        __half2 h = __halves2half2(__float2half(v0), __float2half(v1));
        imgVP[(size_t)(by * 32 + row) * PP + bx * 32 + cl] = *(uint32_t*)&h;
        // vertical pair of PT at (bx*32+row, by*32+cl):
        //   (PT[R][C], PT[R+1][C]) = (P[C][R], P[C][R+1]) = (lds[cl][row], lds[cl][row+1])
        float t0 = lds[cl * 34 + row], t1 = lds[cl * 34 + row + 1];
        __half2 ht = __halves2half2(__float2half(t0), __float2half(t1));
        imgVPT[(size_t)(bx * 32 + row) * PP + by * 32 + cl] = *(uint32_t*)&ht;
    }
}

// Direct-from-L2 radon: no LDS staging, no phases, no barriers in the hot path.
// Block = 256 thr = 64 detectors x 4 i-chunks (128 i each); one angle per block.y.
// Each thread: analytic live-i-range clip (loose, apron-safe), then a tight
// ~16-VALU / 2-load bilinear loop sampling the vertical-pair image from L2
// (2 MB image -> resident in every XCD L2). 4 chunk-partials merged via LDS.
//
// FIX vs R2: affine base now includes the -au*c / -av*c term (u = au*(i-c)+...,
// R2 dropped it -> rays shifted by up to 180 px). Tail handled exactly
// (remainder loop) instead of padded overshoot (which double-counted up to 3
// live samples at interior chunk boundaries).
__global__ __launch_bounds__(256) void radon_kernel(const uint32_t* __restrict__ imgVP,
                                                    const uint32_t* __restrict__ imgVPT,
                                                    const float4* __restrict__ tab,
                                                    const int* __restrict__ flags,
                                                    float* __restrict__ out) {
    __shared__ float red[256];

    const int tid = threadIdx.x;
    const int dl  = tid & 63;
    const int q   = tid >> 6;            // 0..3 : i-chunk
    const int d0  = blockIdx.x * 64;
    const int a   = blockIdx.y;

    const float c = 255.5f;
    const float4 tb = tab[a];
    const float au = tb.x, bus = tb.y, av = tb.z, bvs = tb.w;
    const uint32_t* __restrict__ src = flags[a] ? imgVPT : imgVP;

    // per-thread affine in PADDED coords:  u(i) = au*i + buP  ==  au*(i-c) + bus*(d-c) + c + POFF
    const float xcl = (float)(d0 + dl) - c;
    const float buP = fmaf(bus, xcl, c + (float)POFF) - au * c;
    const float bvP = fmaf(bvs, xcl, c + (float)POFF) - av * c;

    // loose live box in padded coords: [94, 609] (true nonzero box is (95,608)).
    // All kept samples have u,v in [93.99, 609.01] -> taps within rows/cols
    // [93, 610], strictly inside the written 0..703 region; apron taps are
    // exactly 0, so loose clipping is correctness-free.
    int iLo = q * 128, iHi = q * 128 + 127;
    if (fabsf(au) > 1e-6f) {
        float ia = 1.0f / au;
        float t0 = (94.0f - buP) * ia, t1 = (609.0f - buP) * ia;
        float lo = fminf(t0, t1), hi = fmaxf(t0, t1);
        iLo = max(iLo, (int)ceilf(lo));
        iHi = min(iHi, (int)floorf(hi));
    } else if (buP < 94.0f || buP > 609.0f) {
        iHi = iLo - 1;
    }
    if (fabsf(av) > 1e-6f) {
        float ia = 1.0f / av;
        float t0 = (94.0f - bvP) * ia, t1 = (609.0f - bvP) * ia;
        float lo = fminf(t0, t1), hi = fmaxf(t0, t1);
        iLo = max(iLo, (int)ceilf(lo));
        iHi = min(iHi, (int)floorf(hi));
    } else if (bvP < 94.0f || bvP > 609.0f) {
        iHi = iLo - 1;
    }

    float s = 0.0f;
    float fi = (float)iLo;
    auto sample = [&]() {
        float u = fmaf(au, fi, buP);            // fresh fmaf: no drift, no dep chain
        float v = fmaf(av, fi, bvP);
        float wx = __builtin_amdgcn_fractf(u);
        float wy = __builtin_amdgcn_fractf(v);
        int iu = (int)u, iv = (int)v;           // trunc==floor (coords > 0)
        const uint32_t* p = src + iv * PP + iu; // SGPR base + 32b voffset
        H2U P0, P1;
        P0.u = p[0];                            // (top, bottom) at col iu
        P1.u = p[1];                            // (top, bottom) at col iu+1
        hh2 wyv = cvt_pkrtz(1.0f - wy, wy);
        float mx0 = __builtin_amdgcn_fdot2(wyv, P0.h, 0.0f, false);
        float mx1 = __builtin_amdgcn_fdot2(wyv, P1.h, 0.0f, false);
        s = fmaf(wx, mx1 - mx0, s + mx0);       // horizontal lerp, accumulate
        fi += 1.0f;
    };

    if (iHi >= iLo) {
        const int cnt = iHi - iLo + 1;
        const int n4  = cnt >> 2;
        for (int it = 0; it < n4; ++it) {
#pragma unroll
            for (int k = 0; k < 4; ++k) sample();
        }
        const int rem = cnt & 3;
        for (int r2 = 0; r2 < rem; ++r2) sample();   // exact tail: no overshoot
    }

    // merge the 4 i-chunk partials per detector; plain store (sole owner)
    red[tid] = s;
    __syncthreads();
    if (tid < 64) {
        float r = red[tid] + red[tid + 64] + red[tid + 128] + red[tid + 192];
        out[(d0 + tid) * NA + a] = r;
    }
}

extern "C" void kernel_launch(void* const* d_in, const int* in_sizes, int n_in,
                              void* d_out, int out_size, void* d_ws, size_t ws_size,
                              hipStream_t stream) {
    const float* img  = (const float*)d_in[0];
    const int* angles = (const int*)d_in[1];
    float* out = (float*)d_out;
    float* ws  = (float*)d_ws;

    uint32_t* imgVP  = (uint32_t*)(ws + WS_IMGVP);
    uint32_t* imgVPT = (uint32_t*)(ws + WS_IMGVPT);
    float4*   tab    = (float4*)(ws + WS_TAB);
    int*      flags  = (int*)(ws + WS_FLAGS);

    dim3 pgrid(22, 22);
    pad_kernel<<<pgrid, 256, 0, stream>>>(img, angles, imgVP, imgVPT, tab, flags);

    dim3 grid(N / 64, NA);
    radon_kernel<<<grid, 256, 0, stream>>>(imgVP, imgVPT, tab, flags, out);
}